// Round 4
// baseline (201.426 us; speedup 1.0000x reference)
//
#include <hip/hip_runtime.h>
#include <stdint.h>

typedef unsigned long long u64;

// Geometry: 2 batches x 64 depth slices x 256 x 256. 128 slices total.
#define SLICES 128
#define WPS 1024                    // 64-bit words per slice (65536/64)
#define TOTAL_WORDS (SLICES * WPS)  // 131072 words = 1 MB
#define NBLK3 1024                  // blocks for the reduction kernel

// ws layout (u64 words):
//   [0, 131072)              mask bitmap (bit = pixel, global word idx = pix>>6)
//   [131072*(1+pl), ...)     plane pl, pl = 0..4  (d0 value bit-planes)
// partials (float): byte offset 6*131072*8, NBLK3*6 floats; u32 counter after.
// Everything read is fully written each call (poison-safe): k_packdilate
// zeroes counter before k_reduce runs (stream-ordered).

// ---- kernel 1: fused pack + edge + cascaded 3x3 dilation (one block per slice) ----
__global__ __launch_bounds__(256) void k_packdilate(const int* __restrict__ masks,
                                                    u64* __restrict__ mbits,
                                                    u64* __restrict__ planes,
                                                    unsigned* __restrict__ counter) {
    __shared__ u64 packed[WPS];   // 8 KB: ballot results, word-indexed
    __shared__ u64 rows[256][5];  // stride 5 words breaks bank alignment
    __shared__ u64 tmp[256][5];

    const int t = threadIdx.x;       // row this thread owns (after pack)
    const int slice = blockIdx.x;
    if (slice == 0 && t == 0) *counter = 0u;  // for k_reduce's last-block detect

    // -- pack: coalesced dword loads + wave ballot; wave wv covers words [wv*256, wv*256+256) --
    {
        const int wv = t >> 6, lane = t & 63;
        const int* base = masks + (size_t)slice * 65536;
        #pragma unroll 4
        for (int i = 0; i < 256; ++i) {
            int w = (wv << 8) + i;
            int v = base[(w << 6) + lane];   // 64 lanes read 64 consecutive ints
            u64 bal = __ballot(v != 0);
            if (lane == 0) packed[w] = bal;
        }
    }
    __syncthreads();

    // redistribute: thread t owns row t (4 words); coalesced mbits store
    u64 m[4];
    #pragma unroll
    for (int j = 0; j < 4; ++j) {
        m[j] = packed[t * 4 + j];
        rows[t][j] = m[j];
        mbits[(size_t)slice * WPS + t * 4 + j] = m[j];
    }
    __syncthreads();

    // -- edge = m & ~(up & dn & lf & rt), zero-padded borders --
    u64 c[4];
    {
        u64 up[4], dn[4];
        #pragma unroll
        for (int j = 0; j < 4; ++j) {
            up[j] = (t > 0)   ? rows[t - 1][j] : 0ull;
            dn[j] = (t < 255) ? rows[t + 1][j] : 0ull;
        }
        #pragma unroll
        for (int j = 0; j < 4; ++j) {
            u64 lf = (m[j] << 1) | (j > 0 ? (m[j - 1] >> 63) : 0ull);
            u64 rt = (m[j] >> 1) | (j < 3 ? (m[j + 1] << 63) : 0ull);
            c[j] = m[j] & ~(up[j] & dn[j] & lf & rt);
        }
    }

    u64 p[5][4];
    #pragma unroll
    for (int pl = 0; pl < 5; ++pl)
        #pragma unroll
        for (int j = 0; j < 4; ++j) p[pl][j] = 0ull;

    // no barrier needed: first loop iteration only WRITES tmp (untouched so far)

    for (int k = 1; k <= 20; ++k) {
        u64 h[4];
        #pragma unroll
        for (int j = 0; j < 4; ++j) {
            u64 lf = (c[j] << 1) | (j > 0 ? (c[j - 1] >> 63) : 0ull);
            u64 rt = (c[j] >> 1) | (j < 3 ? (c[j + 1] << 63) : 0ull);
            h[j] = c[j] | lf | rt;
            tmp[t][j] = h[j];
        }
        __syncthreads();
        #pragma unroll
        for (int j = 0; j < 4; ++j) {
            u64 u_ = (t > 0)   ? tmp[t - 1][j] : 0ull;
            u64 d_ = (t < 255) ? tmp[t + 1][j] : 0ull;
            u64 n = h[j] | u_ | d_;
            u64 nw = n & ~c[j];
            c[j] = n;
            #pragma unroll
            for (int pl = 0; pl < 5; ++pl)
                if ((k >> pl) & 1) p[pl][j] |= nw;
        }
        int done = ((c[0] & c[1] & c[2] & c[3]) == 0xFFFFFFFFFFFFFFFFull) ? 1 : 0;
        if (__syncthreads_and(done)) break;  // barrier: protects tmp reuse next iter
    }

    // never-covered pixels encode d0 = 21 (0b10101)
    #pragma unroll
    for (int j = 0; j < 4; ++j) {
        u64 u_ = ~c[j];
        p[0][j] |= u_; p[2][j] |= u_; p[4][j] |= u_;
    }

    #pragma unroll
    for (int pl = 0; pl < 5; ++pl)
        #pragma unroll
        for (int j = 0; j < 4; ++j)
            planes[(size_t)pl * TOTAL_WORDS + (size_t)slice * WPS + t * 4 + j] = p[pl][j];
}

// ---- kernel 2: weighted reduction + fused final dice (last-block-done) ----
__global__ __launch_bounds__(256) void k_reduce(const float* __restrict__ outputs,
                                               const u64* __restrict__ mbits,
                                               const u64* __restrict__ planes,
                                               float* __restrict__ partials,
                                               unsigned* __restrict__ counter,
                                               float* __restrict__ out) {
    __shared__ float wtab[22];
    __shared__ float red[4][6];
    __shared__ int sLast;
    const int t = threadIdx.x;
    if (t < 22) wtab[t] = 2.0f / (1.0f + __expf(10.0f * (float)(t + 1) * (1.0f / 22.0f)));
    __syncthreads();

    const int tid = blockIdx.x * 256 + t;  // 0..262143
    float s[2][3];
    #pragma unroll
    for (int b = 0; b < 2; ++b) { s[b][0] = s[b][1] = s[b][2] = 0.0f; }

    #pragma unroll
    for (int b = 0; b < 2; ++b) {
        for (int i = 0; i < 4; ++i) {
            int pix4 = b * 1048576 + i * 262144 + tid;
            int pix = pix4 * 4;           // fits: < 8.4M
            float4 o4 = ((const float4*)outputs)[pix4];
            float ov[4] = {o4.x, o4.y, o4.z, o4.w};
            int widx = pix >> 6;          // 16 consecutive lanes share word → broadcast-coalesced
            int sh = pix & 63;
            u64 mw = mbits[widx];
            u64 p0 = planes[widx];
            u64 p1 = planes[TOTAL_WORDS + widx];
            u64 p2 = planes[2 * TOTAL_WORDS + widx];
            u64 p3 = planes[3 * TOTAL_WORDS + widx];
            u64 p4 = planes[4 * TOTAL_WORDS + widx];
            #pragma unroll
            for (int q = 0; q < 4; ++q) {
                int s2 = sh + q;
                int d0 = (int)((p0 >> s2) & 1ull)
                       | ((int)((p1 >> s2) & 1ull) << 1)
                       | ((int)((p2 >> s2) & 1ull) << 2)
                       | ((int)((p3 >> s2) & 1ull) << 3)
                       | ((int)((p4 >> s2) & 1ull) << 4);
                float w = wtab[d0];
                float ow = ov[q] * w;
                s[b][0] += ow;
                if ((mw >> s2) & 1ull) { s[b][1] += w; s[b][2] += ow; }
            }
        }
    }

    // wave reduce 6 values
    #pragma unroll
    for (int b = 0; b < 2; ++b)
        #pragma unroll
        for (int k = 0; k < 3; ++k) {
            float v = s[b][k];
            #pragma unroll
            for (int off = 32; off > 0; off >>= 1) v += __shfl_down(v, off);
            s[b][k] = v;
        }
    const int lane = t & 63, wv = t >> 6;
    if (lane == 0) {
        #pragma unroll
        for (int b = 0; b < 2; ++b)
            #pragma unroll
            for (int k = 0; k < 3; ++k) red[wv][b * 3 + k] = s[b][k];
    }
    __syncthreads();
    if (t < 6) {
        float v = red[0][t] + red[1][t] + red[2][t] + red[3][t];
        partials[blockIdx.x * 6 + t] = v;   // distinct addresses, plain stores
    }
    __syncthreads();
    if (t == 0) {
        __threadfence();                    // release: partials visible before count bump
        unsigned old = atomicAdd(counter, 1u);   // 1024 total, staggered — trivial contention
        sLast = (old == (unsigned)(NBLK3 - 1)) ? 1 : 0;
    }
    __syncthreads();
    if (sLast) {
        __threadfence();                    // acquire: invalidate L1 before reading partials
        if (t < 64) {                       // exact k_fin body — bit-identical sum order
            float sf[6] = {0, 0, 0, 0, 0, 0};
            for (int i = t; i < NBLK3; i += 64)
                #pragma unroll
                for (int k = 0; k < 6; ++k) sf[k] += partials[i * 6 + k];
            #pragma unroll
            for (int k = 0; k < 6; ++k) {
                float v = sf[k];
                #pragma unroll
                for (int off = 32; off > 0; off >>= 1) v += __shfl_down(v, off);
                sf[k] = v;
            }
            if (t == 0) {
                float loss = 0.0f;
                #pragma unroll
                for (int b = 0; b < 2; ++b) {
                    float A = sf[b * 3 + 0];   // sum(outputs*w)
                    float T = sf[b * 3 + 1];   // sum(m*w)
                    float I = sf[b * 3 + 2];   // sum(outputs*w*m)
                    float l = (T == 0.0f) ? 0.0f : (1.0f - 2.0f * I / (A + T + 2e-6f));
                    loss += l;
                }
                out[0] = 0.5f * loss;
            }
        }
    }
}

extern "C" void kernel_launch(void* const* d_in, const int* in_sizes, int n_in,
                              void* d_out, int out_size, void* d_ws, size_t ws_size,
                              hipStream_t stream) {
    const float* outputs = (const float*)d_in[0];
    const int* masks = (const int*)d_in[1];
    float* out = (float*)d_out;

    u64* mbits = (u64*)d_ws;
    u64* planes = mbits + TOTAL_WORDS;
    float* partials = (float*)((char*)d_ws + (size_t)6 * TOTAL_WORDS * 8);
    unsigned* counter = (unsigned*)(partials + NBLK3 * 6);

    k_packdilate<<<SLICES, 256, 0, stream>>>(masks, mbits, planes, counter);
    k_reduce<<<NBLK3, 256, 0, stream>>>(outputs, mbits, planes, partials, counter, out);
}

// Round 5
// 141.276 us; speedup vs baseline: 1.4258x; 1.4258x over previous
//
#include <hip/hip_runtime.h>
#include <stdint.h>

typedef unsigned long long u64;

// Geometry: 2 batches x 64 depth slices x 256 x 256. 128 slices total.
#define SLICES 128
#define WPS 1024                    // 64-bit words per slice (65536/64)
#define TOTAL_WORDS (SLICES * WPS)  // 131072 words = 1 MB
#define NBLK3 1024                  // blocks for the reduction kernel

// ws layout (u64 words):
//   [0, 131072)              mask bitmap (bit = pixel, global word idx = pix>>6)
//   [131072*(1+pl), ...)     plane pl, pl = 0..4  (d0 value bit-planes)
// partials (float): byte offset 6*131072*8, NBLK3*6 floats; u32 counter after.
// Everything read is fully written each call (poison-safe): k_packdilate
// zeroes counter before k_reduce runs (stream-ordered).

// ---- kernel 1: fused pack + edge + cascaded 3x3 dilation (one block per slice) ----
// Pack = round-3's int4-per-thread version (measured good). Do NOT use
// ballot here: 256 serialized load->ballot per wave at 5% occupancy was
// latency-bound at 110us (round-4 counters: 2.6% HBM, 0.96% VALUBusy).
__global__ __launch_bounds__(256) void k_packdilate(const int* __restrict__ masks,
                                                    u64* __restrict__ mbits,
                                                    u64* __restrict__ planes,
                                                    unsigned* __restrict__ counter) {
    __shared__ u64 rows[256][5];  // stride 5 words breaks bank alignment
    __shared__ u64 tmp[256][5];

    const int t = threadIdx.x;       // row this thread owns
    const int slice = blockIdx.x;
    if (slice == 0 && t == 0) *counter = 0u;  // for k_reduce's last-block detect

    // -- pack: thread t builds its row's 4 bitmap words from 64 int4 loads --
    // (each lane's 64B line feeds 4 consecutive int4 loads -> ~64 live
    //  lines/wave, 256/CU < 512-line L1: no thrash)
    u64 m[4];
    const int4* src = (const int4*)(masks + (size_t)slice * 65536 + t * 256);
    #pragma unroll
    for (int j = 0; j < 4; ++j) {
        u64 w = 0ull;
        #pragma unroll
        for (int g = 0; g < 16; ++g) {
            int4 v = src[j * 16 + g];
            w |= (u64)(v.x != 0) << (g * 4 + 0);
            w |= (u64)(v.y != 0) << (g * 4 + 1);
            w |= (u64)(v.z != 0) << (g * 4 + 2);
            w |= (u64)(v.w != 0) << (g * 4 + 3);
        }
        m[j] = w;
        rows[t][j] = w;
        mbits[(size_t)slice * WPS + t * 4 + j] = w;  // for k_reduce
    }
    __syncthreads();

    // -- edge = m & ~(up & dn & lf & rt), zero-padded borders --
    u64 c[4];
    {
        u64 up[4], dn[4];
        #pragma unroll
        for (int j = 0; j < 4; ++j) {
            up[j] = (t > 0)   ? rows[t - 1][j] : 0ull;
            dn[j] = (t < 255) ? rows[t + 1][j] : 0ull;
        }
        #pragma unroll
        for (int j = 0; j < 4; ++j) {
            u64 lf = (m[j] << 1) | (j > 0 ? (m[j - 1] >> 63) : 0ull);
            u64 rt = (m[j] >> 1) | (j < 3 ? (m[j + 1] << 63) : 0ull);
            c[j] = m[j] & ~(up[j] & dn[j] & lf & rt);
        }
    }

    u64 p[5][4];
    #pragma unroll
    for (int pl = 0; pl < 5; ++pl)
        #pragma unroll
        for (int j = 0; j < 4; ++j) p[pl][j] = 0ull;

    // no barrier needed: first loop iteration only WRITES tmp (untouched so far)

    for (int k = 1; k <= 20; ++k) {
        u64 h[4];
        #pragma unroll
        for (int j = 0; j < 4; ++j) {
            u64 lf = (c[j] << 1) | (j > 0 ? (c[j - 1] >> 63) : 0ull);
            u64 rt = (c[j] >> 1) | (j < 3 ? (c[j + 1] << 63) : 0ull);
            h[j] = c[j] | lf | rt;
            tmp[t][j] = h[j];
        }
        __syncthreads();
        #pragma unroll
        for (int j = 0; j < 4; ++j) {
            u64 u_ = (t > 0)   ? tmp[t - 1][j] : 0ull;
            u64 d_ = (t < 255) ? tmp[t + 1][j] : 0ull;
            u64 n = h[j] | u_ | d_;
            u64 nw = n & ~c[j];
            c[j] = n;
            #pragma unroll
            for (int pl = 0; pl < 5; ++pl)
                if ((k >> pl) & 1) p[pl][j] |= nw;
        }
        int done = ((c[0] & c[1] & c[2] & c[3]) == 0xFFFFFFFFFFFFFFFFull) ? 1 : 0;
        if (__syncthreads_and(done)) break;  // barrier: protects tmp reuse next iter
    }

    // never-covered pixels encode d0 = 21 (0b10101)
    #pragma unroll
    for (int j = 0; j < 4; ++j) {
        u64 u_ = ~c[j];
        p[0][j] |= u_; p[2][j] |= u_; p[4][j] |= u_;
    }

    #pragma unroll
    for (int pl = 0; pl < 5; ++pl)
        #pragma unroll
        for (int j = 0; j < 4; ++j)
            planes[(size_t)pl * TOTAL_WORDS + (size_t)slice * WPS + t * 4 + j] = p[pl][j];
}

// ---- kernel 2: weighted reduction + fused final dice (last-block-done) ----
// (fin-merge verified correct + ~free in round 4: absmax 0.0, k_reduce ~9us)
__global__ __launch_bounds__(256) void k_reduce(const float* __restrict__ outputs,
                                               const u64* __restrict__ mbits,
                                               const u64* __restrict__ planes,
                                               float* __restrict__ partials,
                                               unsigned* __restrict__ counter,
                                               float* __restrict__ out) {
    __shared__ float wtab[22];
    __shared__ float red[4][6];
    __shared__ int sLast;
    const int t = threadIdx.x;
    if (t < 22) wtab[t] = 2.0f / (1.0f + __expf(10.0f * (float)(t + 1) * (1.0f / 22.0f)));
    __syncthreads();

    const int tid = blockIdx.x * 256 + t;  // 0..262143
    float s[2][3];
    #pragma unroll
    for (int b = 0; b < 2; ++b) { s[b][0] = s[b][1] = s[b][2] = 0.0f; }

    #pragma unroll
    for (int b = 0; b < 2; ++b) {
        for (int i = 0; i < 4; ++i) {
            int pix4 = b * 1048576 + i * 262144 + tid;
            int pix = pix4 * 4;           // fits: < 8.4M
            float4 o4 = ((const float4*)outputs)[pix4];
            float ov[4] = {o4.x, o4.y, o4.z, o4.w};
            int widx = pix >> 6;          // 16 consecutive lanes share word -> broadcast-coalesced
            int sh = pix & 63;
            u64 mw = mbits[widx];
            u64 p0 = planes[widx];
            u64 p1 = planes[TOTAL_WORDS + widx];
            u64 p2 = planes[2 * TOTAL_WORDS + widx];
            u64 p3 = planes[3 * TOTAL_WORDS + widx];
            u64 p4 = planes[4 * TOTAL_WORDS + widx];
            #pragma unroll
            for (int q = 0; q < 4; ++q) {
                int s2 = sh + q;
                int d0 = (int)((p0 >> s2) & 1ull)
                       | ((int)((p1 >> s2) & 1ull) << 1)
                       | ((int)((p2 >> s2) & 1ull) << 2)
                       | ((int)((p3 >> s2) & 1ull) << 3)
                       | ((int)((p4 >> s2) & 1ull) << 4);
                float w = wtab[d0];
                float ow = ov[q] * w;
                s[b][0] += ow;
                if ((mw >> s2) & 1ull) { s[b][1] += w; s[b][2] += ow; }
            }
        }
    }

    // wave reduce 6 values
    #pragma unroll
    for (int b = 0; b < 2; ++b)
        #pragma unroll
        for (int k = 0; k < 3; ++k) {
            float v = s[b][k];
            #pragma unroll
            for (int off = 32; off > 0; off >>= 1) v += __shfl_down(v, off);
            s[b][k] = v;
        }
    const int lane = t & 63, wv = t >> 6;
    if (lane == 0) {
        #pragma unroll
        for (int b = 0; b < 2; ++b)
            #pragma unroll
            for (int k = 0; k < 3; ++k) red[wv][b * 3 + k] = s[b][k];
    }
    __syncthreads();
    if (t < 6) {
        float v = red[0][t] + red[1][t] + red[2][t] + red[3][t];
        partials[blockIdx.x * 6 + t] = v;   // distinct addresses, plain stores
    }
    __syncthreads();
    if (t == 0) {
        __threadfence();                    // release: partials visible before count bump
        unsigned old = atomicAdd(counter, 1u);   // 1024 total, staggered
        sLast = (old == (unsigned)(NBLK3 - 1)) ? 1 : 0;
    }
    __syncthreads();
    if (sLast) {
        __threadfence();                    // acquire: before reading other blocks' partials
        if (t < 64) {                       // exact k_fin body -- bit-identical sum order
            float sf[6] = {0, 0, 0, 0, 0, 0};
            for (int i = t; i < NBLK3; i += 64)
                #pragma unroll
                for (int k = 0; k < 6; ++k) sf[k] += partials[i * 6 + k];
            #pragma unroll
            for (int k = 0; k < 6; ++k) {
                float v = sf[k];
                #pragma unroll
                for (int off = 32; off > 0; off >>= 1) v += __shfl_down(v, off);
                sf[k] = v;
            }
            if (t == 0) {
                float loss = 0.0f;
                #pragma unroll
                for (int b = 0; b < 2; ++b) {
                    float A = sf[b * 3 + 0];   // sum(outputs*w)
                    float T = sf[b * 3 + 1];   // sum(m*w)
                    float I = sf[b * 3 + 2];   // sum(outputs*w*m)
                    float l = (T == 0.0f) ? 0.0f : (1.0f - 2.0f * I / (A + T + 2e-6f));
                    loss += l;
                }
                out[0] = 0.5f * loss;
            }
        }
    }
}

extern "C" void kernel_launch(void* const* d_in, const int* in_sizes, int n_in,
                              void* d_out, int out_size, void* d_ws, size_t ws_size,
                              hipStream_t stream) {
    const float* outputs = (const float*)d_in[0];
    const int* masks = (const int*)d_in[1];
    float* out = (float*)d_out;

    u64* mbits = (u64*)d_ws;
    u64* planes = mbits + TOTAL_WORDS;
    float* partials = (float*)((char*)d_ws + (size_t)6 * TOTAL_WORDS * 8);
    unsigned* counter = (unsigned*)(partials + NBLK3 * 6);

    k_packdilate<<<SLICES, 256, 0, stream>>>(masks, mbits, planes, counter);
    k_reduce<<<NBLK3, 256, 0, stream>>>(outputs, mbits, planes, partials, counter, out);
}

// Round 6
// 116.129 us; speedup vs baseline: 1.7345x; 1.2165x over previous
//
#include <hip/hip_runtime.h>
#include <stdint.h>

typedef unsigned long long u64;

// Geometry: 2 batches x 64 depth slices x 256 x 256. 128 slices total.
#define SLICES 128
#define WPS 1024                    // 64-bit words per slice (65536/64)
#define TOTAL_WORDS (SLICES * WPS)  // 131072 words = 1 MB
#define NBLK3 2048                  // blocks for the reduction kernel

// ws layout (u64 words):
//   [0, 131072)              mask bitmap (bit = pixel, global word idx = pix>>6)
//   [131072*(1+pl), ...)     plane pl, pl = 0..4  (d0 value bit-planes)
// partials (float): byte offset 6*131072*8, NBLK3*6 floats.
// Everything read is fully written each call (poison-safe).
//
// Structure notes (measured):
//  - 3 separate kernels is the PROVEN fastest structure (113.1 us round 3).
//  - Fin-merge via __threadfence = +28 us (round 5: per-block L2 writeback/inv
//    thrashes L2, k_reduce 60us @ 27% occ, 4% HBM). Same-line atomics = +17 us
//    (round 1). Serial ballot pack = +88 us (round 4). DO NOT reintroduce.

// ---- kernel 1: fused pack + edge + cascaded 3x3 dilation (one block per slice) ----
__global__ __launch_bounds__(256) void k_packdilate(const int* __restrict__ masks,
                                                    u64* __restrict__ mbits,
                                                    u64* __restrict__ planes) {
    __shared__ u64 rows[256][5];  // stride 5 words breaks bank alignment
    __shared__ u64 tmp[256][5];

    const int t = threadIdx.x;       // row this thread owns
    const int slice = blockIdx.x;

    // -- pack: thread t builds its row's 4 bitmap words from 64 int4 loads --
    u64 m[4];
    const int4* src = (const int4*)(masks + (size_t)slice * 65536 + t * 256);
    #pragma unroll
    for (int j = 0; j < 4; ++j) {
        u64 w = 0ull;
        #pragma unroll
        for (int g = 0; g < 16; ++g) {
            int4 v = src[j * 16 + g];
            w |= (u64)(v.x != 0) << (g * 4 + 0);
            w |= (u64)(v.y != 0) << (g * 4 + 1);
            w |= (u64)(v.z != 0) << (g * 4 + 2);
            w |= (u64)(v.w != 0) << (g * 4 + 3);
        }
        m[j] = w;
        rows[t][j] = w;
        mbits[(size_t)slice * WPS + t * 4 + j] = w;  // for k_reduce
    }
    __syncthreads();

    // -- edge = m & ~(up & dn & lf & rt), zero-padded borders --
    u64 c[4];
    {
        u64 up[4], dn[4];
        #pragma unroll
        for (int j = 0; j < 4; ++j) {
            up[j] = (t > 0)   ? rows[t - 1][j] : 0ull;
            dn[j] = (t < 255) ? rows[t + 1][j] : 0ull;
        }
        #pragma unroll
        for (int j = 0; j < 4; ++j) {
            u64 lf = (m[j] << 1) | (j > 0 ? (m[j - 1] >> 63) : 0ull);
            u64 rt = (m[j] >> 1) | (j < 3 ? (m[j + 1] << 63) : 0ull);
            c[j] = m[j] & ~(up[j] & dn[j] & lf & rt);
        }
    }

    u64 p[5][4];
    #pragma unroll
    for (int pl = 0; pl < 5; ++pl)
        #pragma unroll
        for (int j = 0; j < 4; ++j) p[pl][j] = 0ull;

    // no barrier needed: first loop iteration only WRITES tmp (untouched so far)

    for (int k = 1; k <= 20; ++k) {
        u64 h[4];
        #pragma unroll
        for (int j = 0; j < 4; ++j) {
            u64 lf = (c[j] << 1) | (j > 0 ? (c[j - 1] >> 63) : 0ull);
            u64 rt = (c[j] >> 1) | (j < 3 ? (c[j + 1] << 63) : 0ull);
            h[j] = c[j] | lf | rt;
            tmp[t][j] = h[j];
        }
        __syncthreads();
        #pragma unroll
        for (int j = 0; j < 4; ++j) {
            u64 u_ = (t > 0)   ? tmp[t - 1][j] : 0ull;
            u64 d_ = (t < 255) ? tmp[t + 1][j] : 0ull;
            u64 n = h[j] | u_ | d_;
            u64 nw = n & ~c[j];
            c[j] = n;
            #pragma unroll
            for (int pl = 0; pl < 5; ++pl)
                if ((k >> pl) & 1) p[pl][j] |= nw;
        }
        int done = ((c[0] & c[1] & c[2] & c[3]) == 0xFFFFFFFFFFFFFFFFull) ? 1 : 0;
        if (__syncthreads_and(done)) break;  // barrier: protects tmp reuse next iter
    }

    // never-covered pixels encode d0 = 21 (0b10101)
    #pragma unroll
    for (int j = 0; j < 4; ++j) {
        u64 u_ = ~c[j];
        p[0][j] |= u_; p[2][j] |= u_; p[4][j] |= u_;
    }

    #pragma unroll
    for (int pl = 0; pl < 5; ++pl)
        #pragma unroll
        for (int j = 0; j < 4; ++j)
            planes[(size_t)pl * TOTAL_WORDS + (size_t)slice * WPS + t * 4 + j] = p[pl][j];
}

// ---- kernel 2: weighted reduction over outputs ----
// 2048 blocks: round-5 counters showed 27% occupancy latency-bound at 1024;
// doubling waves doubles outstanding loads (L3-latency hiding).
__global__ __launch_bounds__(256) void k_reduce(const float* __restrict__ outputs,
                                               const u64* __restrict__ mbits,
                                               const u64* __restrict__ planes,
                                               float* __restrict__ partials) {
    __shared__ float wtab[22];
    __shared__ float red[4][6];
    const int t = threadIdx.x;
    if (t < 22) wtab[t] = 2.0f / (1.0f + __expf(10.0f * (float)(t + 1) * (1.0f / 22.0f)));
    __syncthreads();

    const int tid = blockIdx.x * 256 + t;  // 0..524287
    float s[2][3];
    #pragma unroll
    for (int b = 0; b < 2; ++b) { s[b][0] = s[b][1] = s[b][2] = 0.0f; }

    #pragma unroll
    for (int b = 0; b < 2; ++b) {
        #pragma unroll
        for (int i = 0; i < 2; ++i) {
            int pix4 = b * 1048576 + i * 524288 + tid;
            int pix = pix4 * 4;           // fits: < 8.4M
            float4 o4 = ((const float4*)outputs)[pix4];
            float ov[4] = {o4.x, o4.y, o4.z, o4.w};
            int widx = pix >> 6;          // 16 consecutive lanes share word -> broadcast-coalesced
            int sh = pix & 63;
            u64 mw = mbits[widx];
            u64 p0 = planes[widx];
            u64 p1 = planes[TOTAL_WORDS + widx];
            u64 p2 = planes[2 * TOTAL_WORDS + widx];
            u64 p3 = planes[3 * TOTAL_WORDS + widx];
            u64 p4 = planes[4 * TOTAL_WORDS + widx];
            #pragma unroll
            for (int q = 0; q < 4; ++q) {
                int s2 = sh + q;
                int d0 = (int)((p0 >> s2) & 1ull)
                       | ((int)((p1 >> s2) & 1ull) << 1)
                       | ((int)((p2 >> s2) & 1ull) << 2)
                       | ((int)((p3 >> s2) & 1ull) << 3)
                       | ((int)((p4 >> s2) & 1ull) << 4);
                float w = wtab[d0];
                float ow = ov[q] * w;
                s[b][0] += ow;
                if ((mw >> s2) & 1ull) { s[b][1] += w; s[b][2] += ow; }
            }
        }
    }

    // wave reduce 6 values
    #pragma unroll
    for (int b = 0; b < 2; ++b)
        #pragma unroll
        for (int k = 0; k < 3; ++k) {
            float v = s[b][k];
            #pragma unroll
            for (int off = 32; off > 0; off >>= 1) v += __shfl_down(v, off);
            s[b][k] = v;
        }
    const int lane = t & 63, wv = t >> 6;
    if (lane == 0) {
        #pragma unroll
        for (int b = 0; b < 2; ++b)
            #pragma unroll
            for (int k = 0; k < 3; ++k) red[wv][b * 3 + k] = s[b][k];
    }
    __syncthreads();
    if (t < 6) {
        float v = red[0][t] + red[1][t] + red[2][t] + red[3][t];
        partials[blockIdx.x * 6 + t] = v;   // distinct addresses, plain stores
    }
}

// ---- kernel 3: final reduce + dice ----
__global__ __launch_bounds__(64) void k_fin(const float* __restrict__ partials,
                                            float* __restrict__ out) {
    const int lane = threadIdx.x;
    float s[6] = {0, 0, 0, 0, 0, 0};
    for (int i = lane; i < NBLK3; i += 64)
        #pragma unroll
        for (int k = 0; k < 6; ++k) s[k] += partials[i * 6 + k];
    #pragma unroll
    for (int k = 0; k < 6; ++k) {
        float v = s[k];
        #pragma unroll
        for (int off = 32; off > 0; off >>= 1) v += __shfl_down(v, off);
        s[k] = v;
    }
    if (lane == 0) {
        float loss = 0.0f;
        #pragma unroll
        for (int b = 0; b < 2; ++b) {
            float A = s[b * 3 + 0];   // sum(outputs*w)
            float T = s[b * 3 + 1];   // sum(m*w)
            float I = s[b * 3 + 2];   // sum(outputs*w*m)
            float l = (T == 0.0f) ? 0.0f : (1.0f - 2.0f * I / (A + T + 2e-6f));
            loss += l;
        }
        out[0] = 0.5f * loss;
    }
}

extern "C" void kernel_launch(void* const* d_in, const int* in_sizes, int n_in,
                              void* d_out, int out_size, void* d_ws, size_t ws_size,
                              hipStream_t stream) {
    const float* outputs = (const float*)d_in[0];
    const int* masks = (const int*)d_in[1];
    float* out = (float*)d_out;

    u64* mbits = (u64*)d_ws;
    u64* planes = mbits + TOTAL_WORDS;
    float* partials = (float*)((char*)d_ws + (size_t)6 * TOTAL_WORDS * 8);

    k_packdilate<<<SLICES, 256, 0, stream>>>(masks, mbits, planes);
    k_reduce<<<NBLK3, 256, 0, stream>>>(outputs, mbits, planes, partials);
    k_fin<<<1, 64, 0, stream>>>(partials, out);
}

// Round 7
// 113.269 us; speedup vs baseline: 1.7783x; 1.0252x over previous
//
#include <hip/hip_runtime.h>
#include <stdint.h>

typedef unsigned long long u64;

// Geometry: 2 batches x 64 depth slices x 256 x 256. 128 slices total.
#define SLICES 128
#define WPS 1024                    // 64-bit words per slice (65536/64)
#define TOTAL_WORDS (SLICES * WPS)  // 131072 words = 1 MB
#define NBLK3 1024                  // blocks for the reduction kernel

// ws layout (u64 words):
//   [0, 131072)              mask bitmap (bit = pixel, global word idx = pix>>6)
//   [131072*(1+pl), ...)     plane pl, pl = 0..4  (d0 value bit-planes)
// partials (float): byte offset 6*131072*8, NBLK3*6 floats.
// Everything read is fully written each call (poison-safe).
//
// Structure ledger (measured, this session):
//  R3 (this file): 113.1 us  <- best
//  R0 split pack:  115.1     R6 reduce@2048: 116.1   (both ~noise vs R3)
//  R1 same-line atomics fin-merge: +17 us. R5 threadfence fin-merge: +28 us
//  (per-block device-fence = L2 writeback storm). R4 serial ballot pack: +88 us
//  (256 serialized load->ballot at 5% occupancy). DO NOT reintroduce any.
//  Fixed overhead: 2 harness poison-fills ~83 us @ ~6.5 TB/s (untouchable).

// ---- kernel 1: fused pack + edge + cascaded 3x3 dilation (one block per slice) ----
__global__ __launch_bounds__(256) void k_packdilate(const int* __restrict__ masks,
                                                    u64* __restrict__ mbits,
                                                    u64* __restrict__ planes) {
    __shared__ u64 rows[256][5];  // stride 5 words breaks bank alignment
    __shared__ u64 tmp[256][5];

    const int t = threadIdx.x;       // row this thread owns
    const int slice = blockIdx.x;

    // -- pack: thread t builds its row's 4 bitmap words from 64 int4 loads --
    u64 m[4];
    const int4* src = (const int4*)(masks + (size_t)slice * 65536 + t * 256);
    #pragma unroll
    for (int j = 0; j < 4; ++j) {
        u64 w = 0ull;
        #pragma unroll
        for (int g = 0; g < 16; ++g) {
            int4 v = src[j * 16 + g];
            w |= (u64)(v.x != 0) << (g * 4 + 0);
            w |= (u64)(v.y != 0) << (g * 4 + 1);
            w |= (u64)(v.z != 0) << (g * 4 + 2);
            w |= (u64)(v.w != 0) << (g * 4 + 3);
        }
        m[j] = w;
        rows[t][j] = w;
        mbits[(size_t)slice * WPS + t * 4 + j] = w;  // for k_reduce
    }
    __syncthreads();

    // -- edge = m & ~(up & dn & lf & rt), zero-padded borders --
    u64 c[4];
    {
        u64 up[4], dn[4];
        #pragma unroll
        for (int j = 0; j < 4; ++j) {
            up[j] = (t > 0)   ? rows[t - 1][j] : 0ull;
            dn[j] = (t < 255) ? rows[t + 1][j] : 0ull;
        }
        #pragma unroll
        for (int j = 0; j < 4; ++j) {
            u64 lf = (m[j] << 1) | (j > 0 ? (m[j - 1] >> 63) : 0ull);
            u64 rt = (m[j] >> 1) | (j < 3 ? (m[j + 1] << 63) : 0ull);
            c[j] = m[j] & ~(up[j] & dn[j] & lf & rt);
        }
    }

    u64 p[5][4];
    #pragma unroll
    for (int pl = 0; pl < 5; ++pl)
        #pragma unroll
        for (int j = 0; j < 4; ++j) p[pl][j] = 0ull;

    // no barrier needed: first loop iteration only WRITES tmp (untouched so far)

    for (int k = 1; k <= 20; ++k) {
        u64 h[4];
        #pragma unroll
        for (int j = 0; j < 4; ++j) {
            u64 lf = (c[j] << 1) | (j > 0 ? (c[j - 1] >> 63) : 0ull);
            u64 rt = (c[j] >> 1) | (j < 3 ? (c[j + 1] << 63) : 0ull);
            h[j] = c[j] | lf | rt;
            tmp[t][j] = h[j];
        }
        __syncthreads();
        #pragma unroll
        for (int j = 0; j < 4; ++j) {
            u64 u_ = (t > 0)   ? tmp[t - 1][j] : 0ull;
            u64 d_ = (t < 255) ? tmp[t + 1][j] : 0ull;
            u64 n = h[j] | u_ | d_;
            u64 nw = n & ~c[j];
            c[j] = n;
            #pragma unroll
            for (int pl = 0; pl < 5; ++pl)
                if ((k >> pl) & 1) p[pl][j] |= nw;
        }
        int done = ((c[0] & c[1] & c[2] & c[3]) == 0xFFFFFFFFFFFFFFFFull) ? 1 : 0;
        if (__syncthreads_and(done)) break;  // barrier: protects tmp reuse next iter
    }

    // never-covered pixels encode d0 = 21 (0b10101)
    #pragma unroll
    for (int j = 0; j < 4; ++j) {
        u64 u_ = ~c[j];
        p[0][j] |= u_; p[2][j] |= u_; p[4][j] |= u_;
    }

    #pragma unroll
    for (int pl = 0; pl < 5; ++pl)
        #pragma unroll
        for (int j = 0; j < 4; ++j)
            planes[(size_t)pl * TOTAL_WORDS + (size_t)slice * WPS + t * 4 + j] = p[pl][j];
}

// ---- kernel 2: weighted reduction over outputs ----
__global__ __launch_bounds__(256) void k_reduce(const float* __restrict__ outputs,
                                               const u64* __restrict__ mbits,
                                               const u64* __restrict__ planes,
                                               float* __restrict__ partials) {
    __shared__ float wtab[22];
    __shared__ float red[4][6];
    const int t = threadIdx.x;
    if (t < 22) wtab[t] = 2.0f / (1.0f + __expf(10.0f * (float)(t + 1) * (1.0f / 22.0f)));
    __syncthreads();

    const int tid = blockIdx.x * 256 + t;  // 0..262143
    float s[2][3];
    #pragma unroll
    for (int b = 0; b < 2; ++b) { s[b][0] = s[b][1] = s[b][2] = 0.0f; }

    #pragma unroll
    for (int b = 0; b < 2; ++b) {
        for (int i = 0; i < 4; ++i) {
            int pix4 = b * 1048576 + i * 262144 + tid;
            int pix = pix4 * 4;           // fits: < 8.4M
            float4 o4 = ((const float4*)outputs)[pix4];
            float ov[4] = {o4.x, o4.y, o4.z, o4.w};
            int widx = pix >> 6;          // 16 consecutive lanes share word -> broadcast-coalesced
            int sh = pix & 63;
            u64 mw = mbits[widx];
            u64 p0 = planes[widx];
            u64 p1 = planes[TOTAL_WORDS + widx];
            u64 p2 = planes[2 * TOTAL_WORDS + widx];
            u64 p3 = planes[3 * TOTAL_WORDS + widx];
            u64 p4 = planes[4 * TOTAL_WORDS + widx];
            #pragma unroll
            for (int q = 0; q < 4; ++q) {
                int s2 = sh + q;
                int d0 = (int)((p0 >> s2) & 1ull)
                       | ((int)((p1 >> s2) & 1ull) << 1)
                       | ((int)((p2 >> s2) & 1ull) << 2)
                       | ((int)((p3 >> s2) & 1ull) << 3)
                       | ((int)((p4 >> s2) & 1ull) << 4);
                float w = wtab[d0];
                float ow = ov[q] * w;
                s[b][0] += ow;
                if ((mw >> s2) & 1ull) { s[b][1] += w; s[b][2] += ow; }
            }
        }
    }

    // wave reduce 6 values
    #pragma unroll
    for (int b = 0; b < 2; ++b)
        #pragma unroll
        for (int k = 0; k < 3; ++k) {
            float v = s[b][k];
            #pragma unroll
            for (int off = 32; off > 0; off >>= 1) v += __shfl_down(v, off);
            s[b][k] = v;
        }
    const int lane = t & 63, wv = t >> 6;
    if (lane == 0) {
        #pragma unroll
        for (int b = 0; b < 2; ++b)
            #pragma unroll
            for (int k = 0; k < 3; ++k) red[wv][b * 3 + k] = s[b][k];
    }
    __syncthreads();
    if (t < 6) {
        float v = red[0][t] + red[1][t] + red[2][t] + red[3][t];
        partials[blockIdx.x * 6 + t] = v;   // distinct addresses, plain stores
    }
}

// ---- kernel 3: final reduce + dice ----
__global__ __launch_bounds__(64) void k_fin(const float* __restrict__ partials,
                                            float* __restrict__ out) {
    const int lane = threadIdx.x;
    float s[6] = {0, 0, 0, 0, 0, 0};
    for (int i = lane; i < NBLK3; i += 64)
        #pragma unroll
        for (int k = 0; k < 6; ++k) s[k] += partials[i * 6 + k];
    #pragma unroll
    for (int k = 0; k < 6; ++k) {
        float v = s[k];
        #pragma unroll
        for (int off = 32; off > 0; off >>= 1) v += __shfl_down(v, off);
        s[k] = v;
    }
    if (lane == 0) {
        float loss = 0.0f;
        #pragma unroll
        for (int b = 0; b < 2; ++b) {
            float A = s[b * 3 + 0];   // sum(outputs*w)
            float T = s[b * 3 + 1];   // sum(m*w)
            float I = s[b * 3 + 2];   // sum(outputs*w*m)
            float l = (T == 0.0f) ? 0.0f : (1.0f - 2.0f * I / (A + T + 2e-6f));
            loss += l;
        }
        out[0] = 0.5f * loss;
    }
}

extern "C" void kernel_launch(void* const* d_in, const int* in_sizes, int n_in,
                              void* d_out, int out_size, void* d_ws, size_t ws_size,
                              hipStream_t stream) {
    const float* outputs = (const float*)d_in[0];
    const int* masks = (const int*)d_in[1];
    float* out = (float*)d_out;

    u64* mbits = (u64*)d_ws;
    u64* planes = mbits + TOTAL_WORDS;
    float* partials = (float*)((char*)d_ws + (size_t)6 * TOTAL_WORDS * 8);

    k_packdilate<<<SLICES, 256, 0, stream>>>(masks, mbits, planes);
    k_reduce<<<NBLK3, 256, 0, stream>>>(outputs, mbits, planes, partials);
    k_fin<<<1, 64, 0, stream>>>(partials, out);
}